// Round 2
// baseline (663.222 us; speedup 1.0000x reference)
//
#include <hip/hip_runtime.h>
#include <math.h>

#define N_NODES 100000
#define N_EDGES 1600000
#define D 128

#define SCAN_BS 512
#define SCAN_NB 196   // ceil(100000 / 512)

// ---------------- CSR build ----------------

__global__ __launch_bounds__(256) void count_deg(
    const int* __restrict__ dst, int* __restrict__ deg)
{
    int e = blockIdx.x * 256 + threadIdx.x;
    if (e < N_EDGES) atomicAdd(&deg[dst[e]], 1);
}

// exclusive scan, per-block partials (Hillis-Steele in LDS)
__global__ __launch_bounds__(SCAN_BS) void scan_partial(
    const int* __restrict__ deg, int* __restrict__ ptr, int* __restrict__ blockSums)
{
    __shared__ int tmp[SCAN_BS];
    const int tid = threadIdx.x;
    const int i = blockIdx.x * SCAN_BS + tid;
    const int v = (i < N_NODES) ? deg[i] : 0;
    tmp[tid] = v;
    __syncthreads();
    for (int off = 1; off < SCAN_BS; off <<= 1) {
        int t = (tid >= off) ? tmp[tid - off] : 0;
        __syncthreads();
        tmp[tid] += t;
        __syncthreads();
    }
    if (i < N_NODES) ptr[i] = tmp[tid] - v;                  // exclusive
    if (tid == SCAN_BS - 1) blockSums[blockIdx.x] = tmp[tid]; // block total
}

__global__ __launch_bounds__(256) void scan_sums(int* __restrict__ blockSums)
{
    __shared__ int tmp[256];
    const int tid = threadIdx.x;
    const int v = (tid < SCAN_NB) ? blockSums[tid] : 0;
    tmp[tid] = v;
    __syncthreads();
    for (int off = 1; off < 256; off <<= 1) {
        int t = (tid >= off) ? tmp[tid - off] : 0;
        __syncthreads();
        tmp[tid] += t;
        __syncthreads();
    }
    if (tid < SCAN_NB) blockSums[tid] = tmp[tid] - v;        // exclusive offsets
}

__global__ __launch_bounds__(256) void scan_add(
    int* __restrict__ ptr, const int* __restrict__ blockSums)
{
    const int i = blockIdx.x * 256 + threadIdx.x;
    if (i < N_NODES) ptr[i] += blockSums[i / SCAN_BS];
    if (i == 0) ptr[N_NODES] = N_EDGES;
}

__global__ __launch_bounds__(256) void scatter_edges(
    const int* __restrict__ src, const int* __restrict__ dst,
    int* __restrict__ cursor, int* __restrict__ csr_src)
{
    int e = blockIdx.x * 256 + threadIdx.x;
    if (e < N_EDGES) {
        int pos = atomicAdd(&cursor[dst[e]], 1);
        csr_src[pos] = src[e];   // order within a node is arbitrary; max is order-invariant
    }
}

// ---------------- aggregation: combined[i] = x[i] + max_{j in N(i)} x[j] ----------------
// 32 threads per node; lane c handles cols 4c..4c+3. 4-way unrolled gather for MLP.

__global__ __launch_bounds__(256) void agg_combine_kernel(
    const float* __restrict__ x, const int* __restrict__ ptr,
    const int* __restrict__ csr_src, float* __restrict__ combined)
{
    const int gid = blockIdx.x * 256 + threadIdx.x;
    const int row = gid >> 5;
    const int col = (gid & 31) * 4;

    const int beg = ptr[row];
    const int end = ptr[row + 1];

    float4 m0 = make_float4(-INFINITY, -INFINITY, -INFINITY, -INFINITY);
    float4 m1 = m0, m2 = m0, m3 = m0;

    int j = beg;
    for (; j + 4 <= end; j += 4) {
        const int s0 = csr_src[j];
        const int s1 = csr_src[j + 1];
        const int s2 = csr_src[j + 2];
        const int s3 = csr_src[j + 3];
        const float4 v0 = *reinterpret_cast<const float4*>(&x[(long long)s0 * D + col]);
        const float4 v1 = *reinterpret_cast<const float4*>(&x[(long long)s1 * D + col]);
        const float4 v2 = *reinterpret_cast<const float4*>(&x[(long long)s2 * D + col]);
        const float4 v3 = *reinterpret_cast<const float4*>(&x[(long long)s3 * D + col]);
        m0.x = fmaxf(m0.x, v0.x); m0.y = fmaxf(m0.y, v0.y); m0.z = fmaxf(m0.z, v0.z); m0.w = fmaxf(m0.w, v0.w);
        m1.x = fmaxf(m1.x, v1.x); m1.y = fmaxf(m1.y, v1.y); m1.z = fmaxf(m1.z, v1.z); m1.w = fmaxf(m1.w, v1.w);
        m2.x = fmaxf(m2.x, v2.x); m2.y = fmaxf(m2.y, v2.y); m2.z = fmaxf(m2.z, v2.z); m2.w = fmaxf(m2.w, v2.w);
        m3.x = fmaxf(m3.x, v3.x); m3.y = fmaxf(m3.y, v3.y); m3.z = fmaxf(m3.z, v3.z); m3.w = fmaxf(m3.w, v3.w);
    }
    for (; j < end; ++j) {
        const int s = csr_src[j];
        const float4 v = *reinterpret_cast<const float4*>(&x[(long long)s * D + col]);
        m0.x = fmaxf(m0.x, v.x); m0.y = fmaxf(m0.y, v.y); m0.z = fmaxf(m0.z, v.z); m0.w = fmaxf(m0.w, v.w);
    }

    m0.x = fmaxf(fmaxf(m0.x, m1.x), fmaxf(m2.x, m3.x));
    m0.y = fmaxf(fmaxf(m0.y, m1.y), fmaxf(m2.y, m3.y));
    m0.z = fmaxf(fmaxf(m0.z, m1.z), fmaxf(m2.z, m3.z));
    m0.w = fmaxf(fmaxf(m0.w, m1.w), fmaxf(m2.w, m3.w));

    const float4 xv = *reinterpret_cast<const float4*>(&x[(long long)row * D + col]);
    float4 c;
    if (end > beg) {   // non-empty: max of finite inputs is finite
        c.x = xv.x + m0.x; c.y = xv.y + m0.y; c.z = xv.z + m0.z; c.w = xv.w + m0.w;
    } else {           // empty neighborhood -> agg = 0 (reference isfinite guard)
        c = xv;
    }
    *reinterpret_cast<float4*>(&combined[(long long)row * D + col]) = c;
}

// ---------------- GEMM: out = [relu](combined @ W + b) ----------------
// Block 256 = 4 waves; block computes 32 rows. Wave w: 8 rows; half-wave h owns 4.
// Lane: cols (lane&31)*4. One W float4 LDS read feeds 16 FMAs (4 rows x 4 cols).

template<bool RELU>
__global__ __launch_bounds__(256) void gin_gemm_kernel(
    const float* __restrict__ xc, const float* __restrict__ W,
    const float* __restrict__ b, float* __restrict__ out)
{
    __shared__ float Wlds[D * D];       // 64 KB
    __shared__ float rowbuf[32][D];     // 16 KB

    const int tid = threadIdx.x;
    const int rbase = blockIdx.x * 32;

    // stage W (coalesced float4)
    for (int i = tid * 4; i < D * D; i += 256 * 4) {
        *reinterpret_cast<float4*>(&Wlds[i]) = *reinterpret_cast<const float4*>(&W[i]);
    }
    // stage 32 input rows (coalesced float4)
    for (int i = tid; i < 1024; i += 256) {
        const int rl = i >> 5;
        const int c4 = (i & 31) * 4;
        *reinterpret_cast<float4*>(&rowbuf[rl][c4]) =
            *reinterpret_cast<const float4*>(&xc[(long long)(rbase + rl) * D + c4]);
    }
    __syncthreads();

    const int wave = tid >> 6;
    const int lane = tid & 63;
    const int half = lane >> 5;
    const int col  = (lane & 31) * 4;
    const int r0   = wave * 8 + half * 4;   // local row base (4 rows)

    const float4 bias = *reinterpret_cast<const float4*>(&b[col]);
    float4 acc0 = bias, acc1 = bias, acc2 = bias, acc3 = bias;

#pragma unroll 8
    for (int k = 0; k < D; ++k) {
        const float4 w4 = *reinterpret_cast<const float4*>(&Wlds[k * D + col]);
        const float x0 = rowbuf[r0 + 0][k];
        const float x1 = rowbuf[r0 + 1][k];
        const float x2 = rowbuf[r0 + 2][k];
        const float x3 = rowbuf[r0 + 3][k];
        acc0.x = fmaf(x0, w4.x, acc0.x); acc0.y = fmaf(x0, w4.y, acc0.y);
        acc0.z = fmaf(x0, w4.z, acc0.z); acc0.w = fmaf(x0, w4.w, acc0.w);
        acc1.x = fmaf(x1, w4.x, acc1.x); acc1.y = fmaf(x1, w4.y, acc1.y);
        acc1.z = fmaf(x1, w4.z, acc1.z); acc1.w = fmaf(x1, w4.w, acc1.w);
        acc2.x = fmaf(x2, w4.x, acc2.x); acc2.y = fmaf(x2, w4.y, acc2.y);
        acc2.z = fmaf(x2, w4.z, acc2.z); acc2.w = fmaf(x2, w4.w, acc2.w);
        acc3.x = fmaf(x3, w4.x, acc3.x); acc3.y = fmaf(x3, w4.y, acc3.y);
        acc3.z = fmaf(x3, w4.z, acc3.z); acc3.w = fmaf(x3, w4.w, acc3.w);
    }

    if (RELU) {
        acc0.x = fmaxf(acc0.x, 0.f); acc0.y = fmaxf(acc0.y, 0.f); acc0.z = fmaxf(acc0.z, 0.f); acc0.w = fmaxf(acc0.w, 0.f);
        acc1.x = fmaxf(acc1.x, 0.f); acc1.y = fmaxf(acc1.y, 0.f); acc1.z = fmaxf(acc1.z, 0.f); acc1.w = fmaxf(acc1.w, 0.f);
        acc2.x = fmaxf(acc2.x, 0.f); acc2.y = fmaxf(acc2.y, 0.f); acc2.z = fmaxf(acc2.z, 0.f); acc2.w = fmaxf(acc2.w, 0.f);
        acc3.x = fmaxf(acc3.x, 0.f); acc3.y = fmaxf(acc3.y, 0.f); acc3.z = fmaxf(acc3.z, 0.f); acc3.w = fmaxf(acc3.w, 0.f);
    }

    float* o = &out[(long long)(rbase + r0) * D + col];
    *reinterpret_cast<float4*>(&o[0 * D]) = acc0;
    *reinterpret_cast<float4*>(&o[1 * D]) = acc1;
    *reinterpret_cast<float4*>(&o[2 * D]) = acc2;
    *reinterpret_cast<float4*>(&o[3 * D]) = acc3;
}

// ---------------- launch ----------------

extern "C" void kernel_launch(void* const* d_in, const int* in_sizes, int n_in,
                              void* d_out, int out_size, void* d_ws, size_t ws_size,
                              hipStream_t stream) {
    const float* h   = (const float*)d_in[0];
    const int*   src = (const int*)d_in[1];
    const int*   dst = (const int*)d_in[2];
    const float* W1  = (const float*)d_in[3];
    const float* b1  = (const float*)d_in[4];
    const float* W2  = (const float*)d_in[5];
    const float* b2  = (const float*)d_in[6];
    float* out = (float*)d_out;

    // workspace layout (all offsets 16B-aligned)
    int* ptr       = (int*)d_ws;                 // N+1 used (100352 reserved)
    int* cursor    = ptr + 100352;               // N used (doubles as deg buffer)
    int* blockSums = cursor + 100352;            // SCAN_NB used (512 reserved)
    int* csr_src   = blockSums + 512;            // E
    float* combined = (float*)(csr_src + N_EDGES);         // N*D
    float* x1       = combined + (size_t)N_NODES * D;      // N*D

    // ---- CSR build (deg lives in `cursor` buffer) ----
    hipMemsetAsync(cursor, 0, (size_t)N_NODES * sizeof(int), stream);
    count_deg<<<N_EDGES / 256, 256, 0, stream>>>(dst, cursor);
    scan_partial<<<SCAN_NB, SCAN_BS, 0, stream>>>(cursor, ptr, blockSums);
    scan_sums<<<1, 256, 0, stream>>>(blockSums);
    scan_add<<<(N_NODES + 255) / 256, 256, 0, stream>>>(ptr, blockSums);
    hipMemcpyAsync(cursor, ptr, (size_t)N_NODES * sizeof(int),
                   hipMemcpyDeviceToDevice, stream);
    scatter_edges<<<N_EDGES / 256, 256, 0, stream>>>(src, dst, cursor, csr_src);

    // ---- layer 1 ----
    agg_combine_kernel<<<N_NODES * 32 / 256, 256, 0, stream>>>(h, ptr, csr_src, combined);
    gin_gemm_kernel<true><<<N_NODES / 32, 256, 0, stream>>>(combined, W1, b1, x1);

    // ---- layer 2 ----
    agg_combine_kernel<<<N_NODES * 32 / 256, 256, 0, stream>>>(x1, ptr, csr_src, combined);
    gin_gemm_kernel<false><<<N_NODES / 32, 256, 0, stream>>>(combined, W2, b2, out);
}

// Round 3
// 632.735 us; speedup vs baseline: 1.0482x; 1.0482x over previous
//
#include <hip/hip_runtime.h>
#include <math.h>

#define N_NODES 100000
#define N_EDGES 1600000
#define D 128

#define SCAN_BS 512
#define SCAN_NB 196   // ceil(100000 / 512)

#define NB 8                 // dst-range buckets == XCD count
#define NODES_PER_B 12500    // N_NODES / NB
#define BUCKET_CAP 262144    // per-bucket capacity (expected 200K, >>40 sigma safe)
#define EPB 2048             // edges per pass-1 block
#define P1_BLOCKS ((N_EDGES + EPB - 1) / EPB)   // 782
#define P2_CHUNKS 256        // pass-2 blocks per bucket

// ---------------- pass 1: bucket edges by dst range + degree histogram ----------------

__global__ __launch_bounds__(256) void bucket_edges(
    const int* __restrict__ src, const int* __restrict__ dst,
    int* __restrict__ deg, int* __restrict__ bucketBase, int2* __restrict__ bstore)
{
    __shared__ int cnt[NB];
    __shared__ int base_g[NB];
    __shared__ int sbase[NB + 1];
    __shared__ int2 stage[EPB];          // 16 KB

    const int tid = threadIdx.x;
    const long long eb = (long long)blockIdx.x * EPB;

    if (tid < NB) cnt[tid] = 0;
    __syncthreads();

    int mys[8], myd[8], myb[8], myr[8];
    bool val[8];
#pragma unroll
    for (int i = 0; i < 8; ++i) {        // compile-time indices -> registers
        const long long e = eb + tid + i * 256;
        val[i] = (e < N_EDGES);
        if (val[i]) {
            mys[i] = src[e];
            myd[i] = dst[e];
            myb[i] = (int)((unsigned)myd[i] / NODES_PER_B);
            myr[i] = atomicAdd(&cnt[myb[i]], 1);   // LDS rank
            atomicAdd(&deg[myd[i]], 1);            // global histogram (fire-and-forget)
        }
    }
    __syncthreads();

    if (tid == 0) {
        int acc = 0;
#pragma unroll
        for (int b = 0; b < NB; ++b) { sbase[b] = acc; acc += cnt[b]; }
        sbase[NB] = acc;
    }
    __syncthreads();

    if (tid < NB) base_g[tid] = atomicAdd(&bucketBase[tid], cnt[tid]);

#pragma unroll
    for (int i = 0; i < 8; ++i)
        if (val[i]) stage[sbase[myb[i]] + myr[i]] = make_int2(mys[i], myd[i]);
    __syncthreads();

    // copy out: contiguous per-bucket runs (coalesced-ish, ~256-pair runs)
    const int total = sbase[NB];
    for (int s = tid; s < total; s += 256) {
        int b = 0;
#pragma unroll
        for (int k = 1; k < NB; ++k) b += (s >= sbase[k]);
        const int gpos = base_g[b] + (s - sbase[b]);
        bstore[(long long)b * BUCKET_CAP + gpos] = stage[s];
    }
}

// ---------------- exclusive scan of degrees -> ptr ----------------

__global__ __launch_bounds__(SCAN_BS) void scan_partial(
    const int* __restrict__ deg, int* __restrict__ ptr, int* __restrict__ blockSums)
{
    __shared__ int tmp[SCAN_BS];
    const int tid = threadIdx.x;
    const int i = blockIdx.x * SCAN_BS + tid;
    const int v = (i < N_NODES) ? deg[i] : 0;
    tmp[tid] = v;
    __syncthreads();
    for (int off = 1; off < SCAN_BS; off <<= 1) {
        int t = (tid >= off) ? tmp[tid - off] : 0;
        __syncthreads();
        tmp[tid] += t;
        __syncthreads();
    }
    if (i < N_NODES) ptr[i] = tmp[tid] - v;
    if (tid == SCAN_BS - 1) blockSums[blockIdx.x] = tmp[tid];
}

__global__ __launch_bounds__(256) void scan_sums(int* __restrict__ blockSums)
{
    __shared__ int tmp[256];
    const int tid = threadIdx.x;
    const int v = (tid < SCAN_NB) ? blockSums[tid] : 0;
    tmp[tid] = v;
    __syncthreads();
    for (int off = 1; off < 256; off <<= 1) {
        int t = (tid >= off) ? tmp[tid - off] : 0;
        __syncthreads();
        tmp[tid] += t;
        __syncthreads();
    }
    if (tid < SCAN_NB) blockSums[tid] = tmp[tid] - v;
}

__global__ __launch_bounds__(256) void scan_add(
    int* __restrict__ ptr, const int* __restrict__ blockSums)
{
    const int i = blockIdx.x * 256 + threadIdx.x;
    if (i < N_NODES) ptr[i] += blockSums[i / SCAN_BS];
    if (i == 0) ptr[N_NODES] = N_EDGES;
}

// ---------------- pass 2: XCD-local scatter into CSR ----------------
// blockIdx % 8 == bucket -> round-robin block->XCD mapping keeps each csr
// region written by one XCD's L2 (write-combining works).

__global__ __launch_bounds__(256) void scatter_local(
    const int2* __restrict__ bstore, const int* __restrict__ bucketCount,
    int* __restrict__ cursor, int* __restrict__ csr_src)
{
    const int b = blockIdx.x & (NB - 1);
    const int chunk = blockIdx.x >> 3;
    const int n = bucketCount[b];
    const int per = (n + P2_CHUNKS - 1) / P2_CHUNKS;
    const int lo = chunk * per;
    const int hi = min(lo + per, n);
    const int2* bs = bstore + (long long)b * BUCKET_CAP;
    for (int i = lo + (int)threadIdx.x; i < hi; i += 256) {
        const int2 sd = bs[i];
        const int pos = atomicAdd(&cursor[sd.y], 1);
        csr_src[pos] = sd.x;
    }
}

// ---------------- aggregation: combined[i] = x[i] + max_{j in N(i)} x[j] ----------------

__global__ __launch_bounds__(256) void agg_combine_kernel(
    const float* __restrict__ x, const int* __restrict__ ptr,
    const int* __restrict__ csr_src, float* __restrict__ combined)
{
    const int gid = blockIdx.x * 256 + threadIdx.x;
    const int row = gid >> 5;
    const int col = (gid & 31) * 4;

    const int beg = ptr[row];
    const int end = ptr[row + 1];

    float4 m0 = make_float4(-INFINITY, -INFINITY, -INFINITY, -INFINITY);
    float4 m1 = m0, m2 = m0, m3 = m0;

    int j = beg;
    for (; j + 4 <= end; j += 4) {
        const int s0 = csr_src[j];
        const int s1 = csr_src[j + 1];
        const int s2 = csr_src[j + 2];
        const int s3 = csr_src[j + 3];
        const float4 v0 = *reinterpret_cast<const float4*>(&x[(long long)s0 * D + col]);
        const float4 v1 = *reinterpret_cast<const float4*>(&x[(long long)s1 * D + col]);
        const float4 v2 = *reinterpret_cast<const float4*>(&x[(long long)s2 * D + col]);
        const float4 v3 = *reinterpret_cast<const float4*>(&x[(long long)s3 * D + col]);
        m0.x = fmaxf(m0.x, v0.x); m0.y = fmaxf(m0.y, v0.y); m0.z = fmaxf(m0.z, v0.z); m0.w = fmaxf(m0.w, v0.w);
        m1.x = fmaxf(m1.x, v1.x); m1.y = fmaxf(m1.y, v1.y); m1.z = fmaxf(m1.z, v1.z); m1.w = fmaxf(m1.w, v1.w);
        m2.x = fmaxf(m2.x, v2.x); m2.y = fmaxf(m2.y, v2.y); m2.z = fmaxf(m2.z, v2.z); m2.w = fmaxf(m2.w, v2.w);
        m3.x = fmaxf(m3.x, v3.x); m3.y = fmaxf(m3.y, v3.y); m3.z = fmaxf(m3.z, v3.z); m3.w = fmaxf(m3.w, v3.w);
    }
    for (; j < end; ++j) {
        const int s = csr_src[j];
        const float4 v = *reinterpret_cast<const float4*>(&x[(long long)s * D + col]);
        m0.x = fmaxf(m0.x, v.x); m0.y = fmaxf(m0.y, v.y); m0.z = fmaxf(m0.z, v.z); m0.w = fmaxf(m0.w, v.w);
    }

    m0.x = fmaxf(fmaxf(m0.x, m1.x), fmaxf(m2.x, m3.x));
    m0.y = fmaxf(fmaxf(m0.y, m1.y), fmaxf(m2.y, m3.y));
    m0.z = fmaxf(fmaxf(m0.z, m1.z), fmaxf(m2.z, m3.z));
    m0.w = fmaxf(fmaxf(m0.w, m1.w), fmaxf(m2.w, m3.w));

    const float4 xv = *reinterpret_cast<const float4*>(&x[(long long)row * D + col]);
    float4 c;
    if (end > beg) {
        c.x = xv.x + m0.x; c.y = xv.y + m0.y; c.z = xv.z + m0.z; c.w = xv.w + m0.w;
    } else {
        c = xv;   // empty neighborhood -> agg = 0
    }
    *reinterpret_cast<float4*>(&combined[(long long)row * D + col]) = c;
}

// ---------------- GEMM: out = [relu](combined @ W + b) ----------------

template<bool RELU>
__global__ __launch_bounds__(256) void gin_gemm_kernel(
    const float* __restrict__ xc, const float* __restrict__ W,
    const float* __restrict__ b, float* __restrict__ out)
{
    __shared__ float Wlds[D * D];       // 64 KB
    __shared__ float rowbuf[32][D];     // 16 KB

    const int tid = threadIdx.x;
    const int rbase = blockIdx.x * 32;

    for (int i = tid * 4; i < D * D; i += 256 * 4) {
        *reinterpret_cast<float4*>(&Wlds[i]) = *reinterpret_cast<const float4*>(&W[i]);
    }
    for (int i = tid; i < 1024; i += 256) {
        const int rl = i >> 5;
        const int c4 = (i & 31) * 4;
        *reinterpret_cast<float4*>(&rowbuf[rl][c4]) =
            *reinterpret_cast<const float4*>(&xc[(long long)(rbase + rl) * D + c4]);
    }
    __syncthreads();

    const int wave = tid >> 6;
    const int lane = tid & 63;
    const int half = lane >> 5;
    const int col  = (lane & 31) * 4;
    const int r0   = wave * 8 + half * 4;

    const float4 bias = *reinterpret_cast<const float4*>(&b[col]);
    float4 acc0 = bias, acc1 = bias, acc2 = bias, acc3 = bias;

#pragma unroll 8
    for (int k = 0; k < D; ++k) {
        const float4 w4 = *reinterpret_cast<const float4*>(&Wlds[k * D + col]);
        const float x0 = rowbuf[r0 + 0][k];
        const float x1 = rowbuf[r0 + 1][k];
        const float x2 = rowbuf[r0 + 2][k];
        const float x3 = rowbuf[r0 + 3][k];
        acc0.x = fmaf(x0, w4.x, acc0.x); acc0.y = fmaf(x0, w4.y, acc0.y);
        acc0.z = fmaf(x0, w4.z, acc0.z); acc0.w = fmaf(x0, w4.w, acc0.w);
        acc1.x = fmaf(x1, w4.x, acc1.x); acc1.y = fmaf(x1, w4.y, acc1.y);
        acc1.z = fmaf(x1, w4.z, acc1.z); acc1.w = fmaf(x1, w4.w, acc1.w);
        acc2.x = fmaf(x2, w4.x, acc2.x); acc2.y = fmaf(x2, w4.y, acc2.y);
        acc2.z = fmaf(x2, w4.z, acc2.z); acc2.w = fmaf(x2, w4.w, acc2.w);
        acc3.x = fmaf(x3, w4.x, acc3.x); acc3.y = fmaf(x3, w4.y, acc3.y);
        acc3.z = fmaf(x3, w4.z, acc3.z); acc3.w = fmaf(x3, w4.w, acc3.w);
    }

    if (RELU) {
        acc0.x = fmaxf(acc0.x, 0.f); acc0.y = fmaxf(acc0.y, 0.f); acc0.z = fmaxf(acc0.z, 0.f); acc0.w = fmaxf(acc0.w, 0.f);
        acc1.x = fmaxf(acc1.x, 0.f); acc1.y = fmaxf(acc1.y, 0.f); acc1.z = fmaxf(acc1.z, 0.f); acc1.w = fmaxf(acc1.w, 0.f);
        acc2.x = fmaxf(acc2.x, 0.f); acc2.y = fmaxf(acc2.y, 0.f); acc2.z = fmaxf(acc2.z, 0.f); acc2.w = fmaxf(acc2.w, 0.f);
        acc3.x = fmaxf(acc3.x, 0.f); acc3.y = fmaxf(acc3.y, 0.f); acc3.z = fmaxf(acc3.z, 0.f); acc3.w = fmaxf(acc3.w, 0.f);
    }

    float* o = &out[(long long)(rbase + r0) * D + col];
    *reinterpret_cast<float4*>(&o[0 * D]) = acc0;
    *reinterpret_cast<float4*>(&o[1 * D]) = acc1;
    *reinterpret_cast<float4*>(&o[2 * D]) = acc2;
    *reinterpret_cast<float4*>(&o[3 * D]) = acc3;
}

// ---------------- launch ----------------

extern "C" void kernel_launch(void* const* d_in, const int* in_sizes, int n_in,
                              void* d_out, int out_size, void* d_ws, size_t ws_size,
                              hipStream_t stream) {
    const float* h   = (const float*)d_in[0];
    const int*   src = (const int*)d_in[1];
    const int*   dst = (const int*)d_in[2];
    const float* W1  = (const float*)d_in[3];
    const float* b1  = (const float*)d_in[4];
    const float* W2  = (const float*)d_in[5];
    const float* b2  = (const float*)d_in[6];
    float* out = (float*)d_out;

    // workspace layout
    int* ptr        = (int*)d_ws;                  // [100352]
    int* cursor     = ptr + 100352;                // [100352] (doubles as deg)
    int* blockSums  = cursor + 100352;             // [512]
    int* bucketBase = blockSums + 512;             // [512 reserved; 8 used]
    int* csr_src    = bucketBase + 512;            // [E]
    float* combined = (float*)(csr_src + N_EDGES); // [N*D]; aliased as bucket store during build
    float* x1       = combined + (size_t)N_NODES * D;

    int2* bstore = (int2*)combined;                // 8 * 262144 * 8B = 16 MB < 51.2 MB

    // ---- CSR build ----
    hipMemsetAsync(cursor, 0, (size_t)N_NODES * sizeof(int), stream);
    hipMemsetAsync(bucketBase, 0, NB * sizeof(int), stream);
    bucket_edges<<<P1_BLOCKS, 256, 0, stream>>>(src, dst, cursor, bucketBase, bstore);
    scan_partial<<<SCAN_NB, SCAN_BS, 0, stream>>>(cursor, ptr, blockSums);
    scan_sums<<<1, 256, 0, stream>>>(blockSums);
    scan_add<<<(N_NODES + 255) / 256, 256, 0, stream>>>(ptr, blockSums);
    hipMemcpyAsync(cursor, ptr, (size_t)N_NODES * sizeof(int),
                   hipMemcpyDeviceToDevice, stream);
    scatter_local<<<NB * P2_CHUNKS, 256, 0, stream>>>(bstore, bucketBase, cursor, csr_src);

    // ---- layer 1 ----
    agg_combine_kernel<<<N_NODES * 32 / 256, 256, 0, stream>>>(h, ptr, csr_src, combined);
    gin_gemm_kernel<true><<<N_NODES / 32, 256, 0, stream>>>(combined, W1, b1, x1);

    // ---- layer 2 ----
    agg_combine_kernel<<<N_NODES * 32 / 256, 256, 0, stream>>>(x1, ptr, csr_src, combined);
    gin_gemm_kernel<false><<<N_NODES / 32, 256, 0, stream>>>(combined, W2, b2, out);
}